// Round 1
// baseline (619.465 us; speedup 1.0000x reference)
//
#include <hip/hip_runtime.h>
#include <hip/hip_bf16.h>

constexpr int BB = 4;
constexpr int SS = 2048;
constexpr int DD = 768;
constexpr int HH = 12;
constexpr int DKK = 64;
constexpr int DFF2 = 3072;
constexpr int MR = BB * SS;   // 8192 rows

typedef __attribute__((ext_vector_type(4))) short short4v;
typedef __attribute__((ext_vector_type(8))) short short8v;
typedef __attribute__((ext_vector_type(4))) float f32x4;
typedef __attribute__((ext_vector_type(4))) float float4v;

static __device__ inline short f2bs(float f) {
    __hip_bfloat16 h = __float2bfloat16(f);
    return (short)__builtin_bit_cast(unsigned short, h);
}
static __device__ inline float bs2f(short s) {
    __hip_bfloat16 h = __builtin_bit_cast(__hip_bfloat16, (unsigned short)s);
    return __bfloat162float(h);
}

// ---------------- cast fp32 -> bf16 ----------------
__global__ __launch_bounds__(256) void cast_f32_bf16(const float* __restrict__ in,
                                                     short* __restrict__ out, int n) {
    int i = (blockIdx.x * 256 + threadIdx.x) * 4;
    if (i < n) {
        float4v v = *(const float4v*)&in[i];
        short4v o;
        o[0] = f2bs(v[0]); o[1] = f2bs(v[1]); o[2] = f2bs(v[2]); o[3] = f2bs(v[3]);
        *(short4v*)&out[i] = o;
    }
}

// ---------------- transpose + cast: Wt[n][k] = W[k][n] ----------------
__global__ __launch_bounds__(256) void transpose_cast(const float* __restrict__ W,
                                                      short* __restrict__ Wt, int K, int N) {
    __shared__ float tile[32][33];
    int n0 = blockIdx.x * 32, k0 = blockIdx.y * 32;
    int tx = threadIdx.x & 31, ty = threadIdx.x >> 5;
    #pragma unroll
    for (int i = 0; i < 32; i += 8)
        tile[ty + i][tx] = W[(size_t)(k0 + ty + i) * N + n0 + tx];
    __syncthreads();
    #pragma unroll
    for (int i = 0; i < 32; i += 8)
        Wt[(size_t)(n0 + ty + i) * K + k0 + tx] = f2bs(tile[tx][ty + i]);
}

// ---------------- GEMM: C[M][N] = A[M][K] @ Bt[N][K]^T, bf16 MFMA ----------------
// EPI: 0 = +bias, store bf16 row-major
//      1 = +bias, relu, store bf16 row-major
//      2 = QKV scatter: +bias{q,k,v}, q*=0.125, store bf16 [B,H,S,64]
template <int EPI>
__global__ __launch_bounds__(256) void gemm_bt(
    const short* __restrict__ A, const short* __restrict__ Bt,
    int Mn, int Nn, int Kn,
    const float* __restrict__ bias0, const float* __restrict__ bias1,
    const float* __restrict__ bias2,
    short* __restrict__ out0, short* __restrict__ out1, short* __restrict__ out2) {
    __shared__ short sA[128][36];
    __shared__ short sB[128][36];
    const int tid = threadIdx.x;
    const int wave = tid >> 6, lane = tid & 63;
    const int g = lane >> 4, qq = lane & 15;
    const int wm = (wave >> 1) * 64, wn = (wave & 1) * 64;
    const int m0 = blockIdx.y * 128, n0 = blockIdx.x * 128;

    const f32x4 zero = {0.0f, 0.0f, 0.0f, 0.0f};
    f32x4 acc[4][4];
    #pragma unroll
    for (int i = 0; i < 4; i++)
        #pragma unroll
        for (int j = 0; j < 4; j++) acc[i][j] = zero;

    for (int k0 = 0; k0 < Kn; k0 += 32) {
        __syncthreads();
        #pragma unroll
        for (int i = 0; i < 4; i++) {
            int e = (tid + i * 256) * 4;
            int r = e >> 5, c = e & 31;
            *(short4v*)&sA[r][c] = *(const short4v*)&A[(size_t)(m0 + r) * Kn + k0 + c];
            *(short4v*)&sB[r][c] = *(const short4v*)&Bt[(size_t)(n0 + r) * Kn + k0 + c];
        }
        __syncthreads();
        short8v af[4], bf[4];
        #pragma unroll
        for (int i = 0; i < 4; i++) {
            short4v lo = *(const short4v*)&sA[wm + i * 16 + qq][4 * g];
            short4v hi = *(const short4v*)&sA[wm + i * 16 + qq][16 + 4 * g];
            af[i] = __builtin_shufflevector(lo, hi, 0, 1, 2, 3, 4, 5, 6, 7);
            short4v blo = *(const short4v*)&sB[wn + i * 16 + qq][4 * g];
            short4v bhi = *(const short4v*)&sB[wn + i * 16 + qq][16 + 4 * g];
            bf[i] = __builtin_shufflevector(blo, bhi, 0, 1, 2, 3, 4, 5, 6, 7);
        }
        #pragma unroll
        for (int i = 0; i < 4; i++)
            #pragma unroll
            for (int j = 0; j < 4; j++)
                acc[i][j] = __builtin_amdgcn_mfma_f32_16x16x32_bf16(af[i], bf[j], acc[i][j], 0, 0, 0);
    }

    if (EPI == 2) {
        int which = n0 / DD;
        const float* bias = (which == 0) ? bias0 : ((which == 1) ? bias1 : bias2);
        short* outp = (which == 0) ? out0 : ((which == 1) ? out1 : out2);
        float scale = (which == 0) ? 0.125f : 1.0f;
        #pragma unroll
        for (int i = 0; i < 4; i++)
            #pragma unroll
            for (int j = 0; j < 4; j++)
                #pragma unroll
                for (int r = 0; r < 4; r++) {
                    int row = m0 + wm + i * 16 + g * 4 + r;
                    int col = n0 - which * DD + wn + j * 16 + qq;
                    float vv = (acc[i][j][r] + bias[col]) * scale;
                    int b_ = row >> 11, s_ = row & 2047;
                    int h_ = col >> 6, d_ = col & 63;
                    outp[(((size_t)(b_ * HH + h_)) * SS + s_) * DKK + d_] = f2bs(vv);
                }
    } else {
        #pragma unroll
        for (int i = 0; i < 4; i++)
            #pragma unroll
            for (int j = 0; j < 4; j++)
                #pragma unroll
                for (int r = 0; r < 4; r++) {
                    int row = m0 + wm + i * 16 + g * 4 + r;
                    int col = n0 + wn + j * 16 + qq;
                    float vv = acc[i][j][r] + bias0[col];
                    if (EPI == 1) vv = fmaxf(vv, 0.0f);
                    out0[(size_t)row * Nn + col] = f2bs(vv);
                }
    }
}

// ---------------- flash attention ----------------
// grid: (SS/64, BB*HH), block 256. Q pre-scaled by 1/sqrt(dk).
__global__ __launch_bounds__(256) void attn_kernel(
    const short* __restrict__ Q, const short* __restrict__ Kb,
    const short* __restrict__ Vb, const int* __restrict__ mask,
    short* __restrict__ ctx) {
    __shared__ short sK[32][68];
    __shared__ short sVt[64][36];
    __shared__ short sP[4][16][36];
    const int tid = threadIdx.x;
    const int wave = tid >> 6, lane = tid & 63;
    const int g = lane >> 4, qq = lane & 15;
    const int bh = blockIdx.y;
    const int b_ = bh / HH;
    const int h_ = bh % HH;
    const int q0 = blockIdx.x * 64 + wave * 16;
    const size_t base = (size_t)bh * SS * DKK;
    const float L2E = 1.44269504088896f;

    // Q fragments (A operand), per-wave 16 rows
    short8v aq[2];
    #pragma unroll
    for (int c = 0; c < 2; c++) {
        const short* qp = &Q[base + (size_t)(q0 + qq) * DKK + c * 32 + 4 * g];
        short4v lo = *(const short4v*)qp;
        short4v hi = *(const short4v*)(qp + 16);
        aq[c] = __builtin_shufflevector(lo, hi, 0, 1, 2, 3, 4, 5, 6, 7);
    }

    const f32x4 zero = {0.0f, 0.0f, 0.0f, 0.0f};
    f32x4 cacc[4];
    #pragma unroll
    for (int i = 0; i < 4; i++) cacc[i] = zero;
    float mrow[4], lrow[4];
    #pragma unroll
    for (int r = 0; r < 4; r++) { mrow[r] = -INFINITY; lrow[r] = 0.0f; }

    for (int kv0 = 0; kv0 < SS; kv0 += 32) {
        __syncthreads();
        #pragma unroll
        for (int i = 0; i < 2; i++) {
            int e = (tid + i * 256) * 4;
            int r = e >> 6, c = e & 63;
            *(short4v*)&sK[r][c] = *(const short4v*)&Kb[base + (size_t)(kv0 + r) * DKK + c];
            short4v vv = *(const short4v*)&Vb[base + (size_t)(kv0 + r) * DKK + c];
            sVt[c + 0][r] = vv[0]; sVt[c + 1][r] = vv[1];
            sVt[c + 2][r] = vv[2]; sVt[c + 3][r] = vv[3];
        }
        __syncthreads();

        // scores = Q @ K^T  (two 16-col fragments)
        f32x4 sc[2];
        #pragma unroll
        for (int nf = 0; nf < 2; nf++) {
            f32x4 z = zero;
            #pragma unroll
            for (int c = 0; c < 2; c++) {
                short4v lo = *(const short4v*)&sK[nf * 16 + qq][c * 32 + 4 * g];
                short4v hi = *(const short4v*)&sK[nf * 16 + qq][c * 32 + 16 + 4 * g];
                short8v kf = __builtin_shufflevector(lo, hi, 0, 1, 2, 3, 4, 5, 6, 7);
                z = __builtin_amdgcn_mfma_f32_16x16x32_bf16(aq[c], kf, z, 0, 0, 0);
            }
            sc[nf] = z;
        }
        // mask (column-wise)
        int mv0 = mask[b_ * SS + kv0 + qq];
        int mv1 = mask[b_ * SS + kv0 + 16 + qq];
        if (mv0 == 0) {
            #pragma unroll
            for (int r = 0; r < 4; r++) sc[0][r] = -1e9f;
        }
        if (mv1 == 0) {
            #pragma unroll
            for (int r = 0; r < 4; r++) sc[1][r] = -1e9f;
        }

        // online softmax per row (row index = 4*g + r within the 16-row tile)
        #pragma unroll
        for (int r = 0; r < 4; r++) {
            float t = fmaxf(sc[0][r], sc[1][r]);
            t = fmaxf(t, __shfl_xor(t, 1));
            t = fmaxf(t, __shfl_xor(t, 2));
            t = fmaxf(t, __shfl_xor(t, 4));
            t = fmaxf(t, __shfl_xor(t, 8));
            float mnew = fmaxf(mrow[r], t);
            float alpha = exp2f((mrow[r] - mnew) * L2E);
            mrow[r] = mnew;
            float p0 = exp2f((sc[0][r] - mnew) * L2E);
            float p1 = exp2f((sc[1][r] - mnew) * L2E);
            sc[0][r] = p0; sc[1][r] = p1;
            float rs = p0 + p1;
            rs += __shfl_xor(rs, 1); rs += __shfl_xor(rs, 2);
            rs += __shfl_xor(rs, 4); rs += __shfl_xor(rs, 8);
            lrow[r] = lrow[r] * alpha + rs;
            #pragma unroll
            for (int nf = 0; nf < 4; nf++) cacc[nf][r] *= alpha;
        }

        // P -> LDS (wave-private), then read back as MFMA A-fragments
        #pragma unroll
        for (int r = 0; r < 4; r++) {
            sP[wave][g * 4 + r][qq] = f2bs(sc[0][r]);
            sP[wave][g * 4 + r][16 + qq] = f2bs(sc[1][r]);
        }
        __syncthreads();
        short4v plo = *(const short4v*)&sP[wave][qq][4 * g];
        short4v phi = *(const short4v*)&sP[wave][qq][16 + 4 * g];
        short8v pa = __builtin_shufflevector(plo, phi, 0, 1, 2, 3, 4, 5, 6, 7);
        #pragma unroll
        for (int nf = 0; nf < 4; nf++) {
            short4v blo = *(const short4v*)&sVt[nf * 16 + qq][4 * g];
            short4v bhi = *(const short4v*)&sVt[nf * 16 + qq][16 + 4 * g];
            short8v vf = __builtin_shufflevector(blo, bhi, 0, 1, 2, 3, 4, 5, 6, 7);
            cacc[nf] = __builtin_amdgcn_mfma_f32_16x16x32_bf16(pa, vf, cacc[nf], 0, 0, 0);
        }
    }

    // write ctx [B,S,D] with col = h*64 + dk
    #pragma unroll
    for (int nf = 0; nf < 4; nf++)
        #pragma unroll
        for (int r = 0; r < 4; r++) {
            int row = q0 + g * 4 + r;
            int col = h_ * DKK + nf * 16 + qq;
            float vv = cacc[nf][r] / lrow[r];
            ctx[(size_t)(b_ * SS + row) * DD + col] = f2bs(vv);
        }
}

// ---------------- layernorm: out = LN(in1 + in2) ----------------
// IN1F32: in1 is fp32 (else bf16). OUTF32: out fp32 (else bf16).
template <int IN1F32, int OUTF32>
__global__ __launch_bounds__(256) void ln_kernel(
    const void* __restrict__ in1v, const short* __restrict__ in2,
    const float* __restrict__ gw, const float* __restrict__ bw,
    void* __restrict__ outv) {
    const int row = blockIdx.x;
    const int tid = threadIdx.x;
    float v[3];
    #pragma unroll
    for (int i = 0; i < 3; i++) {
        int c = tid + i * 256;
        float a = IN1F32 ? ((const float*)in1v)[(size_t)row * DD + c]
                         : bs2f(((const short*)in1v)[(size_t)row * DD + c]);
        v[i] = a + bs2f(in2[(size_t)row * DD + c]);
    }
    float s = v[0] + v[1] + v[2];
    float s2 = v[0] * v[0] + v[1] * v[1] + v[2] * v[2];
    #pragma unroll
    for (int off = 1; off < 64; off <<= 1) {
        s += __shfl_xor(s, off);
        s2 += __shfl_xor(s2, off);
    }
    __shared__ float red[8];
    int wv = tid >> 6;
    if ((tid & 63) == 0) { red[wv] = s; red[4 + wv] = s2; }
    __syncthreads();
    s = red[0] + red[1] + red[2] + red[3];
    s2 = red[4] + red[5] + red[6] + red[7];
    float mu = s / DD;
    float var = s2 / DD - mu * mu;
    float rs = rsqrtf(var + 1e-5f);
    #pragma unroll
    for (int i = 0; i < 3; i++) {
        int c = tid + i * 256;
        float y = (v[i] - mu) * rs * gw[c] + bw[c];
        if (OUTF32) ((float*)outv)[(size_t)row * DD + c] = y;
        else ((short*)outv)[(size_t)row * DD + c] = f2bs(y);
    }
}

extern "C" void kernel_launch(void* const* d_in, const int* in_sizes, int n_in,
                              void* d_out, int out_size, void* d_ws, size_t ws_size,
                              hipStream_t stream) {
    (void)in_sizes; (void)n_in; (void)out_size; (void)ws_size;
    const float* src = (const float*)d_in[0];
    const int* mask = (const int*)d_in[1];
    const float* Wq = (const float*)d_in[2];
    const float* bq = (const float*)d_in[3];
    const float* Wk = (const float*)d_in[4];
    const float* bk = (const float*)d_in[5];
    const float* Wv = (const float*)d_in[6];
    const float* bv = (const float*)d_in[7];
    const float* Wo = (const float*)d_in[8];
    const float* bo = (const float*)d_in[9];
    const float* W1 = (const float*)d_in[10];
    const float* b1 = (const float*)d_in[11];
    const float* W2 = (const float*)d_in[12];
    const float* b2 = (const float*)d_in[13];
    const float* ln1_g = (const float*)d_in[14];
    const float* ln1_b = (const float*)d_in[15];
    const float* ln2_g = (const float*)d_in[16];
    const float* ln2_b = (const float*)d_in[17];

    char* ws = (char*)d_ws;
    const size_t SB = (size_t)MR * DD * 2;            // 12582912 bytes (one [8192,768] bf16)
    short* src_b  = (short*)(ws);                     // R0: src_bf16 / attn_out / ffn2_out
    short* Wqkv_t = (short*)(ws + SB);                // R1
    short* qb     = (short*)(ws + SB + 3538944);      // R2: q,k,v,ctx  (h aliases all of R2)
    short* kb_    = qb + (size_t)MR * DD;
    short* vb_    = kb_ + (size_t)MR * DD;
    short* ctxb   = vb_ + (size_t)MR * DD;
    short* hb     = qb;                               // [8192,3072] bf16, aliases q/k/v/ctx
    short* Wo_t   = (short*)(ws + SB + 3538944 + 4 * SB);          // R3
    short* x_b    = (short*)(ws + SB + 3538944 + 4 * SB + 1179648);// R4
    short* W1_t   = (short*)((char*)x_b + SB);                     // R5
    short* W2_t   = (short*)((char*)W1_t + 4718592);               // R6
    float* x_f    = (float*)((char*)W2_t + 4718592);               // R7: fp32 x for residual
    short* attn_b = src_b;
    short* ffn_b  = src_b;

    // 1. casts / transposes
    cast_f32_bf16<<<(MR * DD) / 1024, 256, 0, stream>>>(src, src_b, MR * DD);
    transpose_cast<<<dim3(24, 24), 256, 0, stream>>>(Wq, Wqkv_t, DD, DD);
    transpose_cast<<<dim3(24, 24), 256, 0, stream>>>(Wk, Wqkv_t + DD * DD, DD, DD);
    transpose_cast<<<dim3(24, 24), 256, 0, stream>>>(Wv, Wqkv_t + 2 * DD * DD, DD, DD);
    transpose_cast<<<dim3(24, 24), 256, 0, stream>>>(Wo, Wo_t, DD, DD);
    transpose_cast<<<dim3(96, 24), 256, 0, stream>>>(W1, W1_t, DD, DFF2);
    transpose_cast<<<dim3(24, 96), 256, 0, stream>>>(W2, W2_t, DFF2, DD);

    // 2. QKV projection (fused, N=2304) with scatter epilogue
    gemm_bt<2><<<dim3(2304 / 128, MR / 128), 256, 0, stream>>>(
        src_b, Wqkv_t, MR, 2304, DD, bq, bk, bv, qb, kb_, vb_);

    // 3. attention
    attn_kernel<<<dim3(SS / 64, BB * HH), 256, 0, stream>>>(qb, kb_, vb_, mask, ctxb);

    // 4. output projection
    gemm_bt<0><<<dim3(DD / 128, MR / 128), 256, 0, stream>>>(
        ctxb, Wo_t, MR, DD, DD, bo, nullptr, nullptr, attn_b, nullptr, nullptr);

    // 5. LN1: x = LN(src + attn_out) -> bf16 (gemm input) + fp32 (residual)
    ln_kernel<1, 0><<<MR, 256, 0, stream>>>(src, attn_b, ln1_g, ln1_b, x_b);
    ln_kernel<1, 1><<<MR, 256, 0, stream>>>(src, attn_b, ln1_g, ln1_b, x_f);

    // 6. FFN
    gemm_bt<1><<<dim3(DFF2 / 128, MR / 128), 256, 0, stream>>>(
        x_b, W1_t, MR, DFF2, DD, b1, nullptr, nullptr, hb, nullptr, nullptr);
    gemm_bt<0><<<dim3(DD / 128, MR / 128), 256, 0, stream>>>(
        hb, W2_t, MR, DD, DFF2, b2, nullptr, nullptr, ffn_b, nullptr, nullptr);

    // 7. LN2 -> fp32 output
    ln_kernel<1, 1><<<MR, 256, 0, stream>>>(x_f, ffn_b, ln2_g, ln2_b, (float*)d_out);
}